// Round 1
// baseline (461.520 us; speedup 1.0000x reference)
//
#include <hip/hip_runtime.h>
#include <math.h>

// Node2GraphAttention: out[g] = sum_{i: batch[i]==g} sigmoid(<n_i, g_emb[g]>) * n_i
// N=500000, D=128, G=10000, n_batch sorted ascending.
//
// Strategy: one wave per contiguous node range. Lane l owns columns {2l, 2l+1}.
// Dot product via 6-step __shfl_xor over the 64-lane wave. Because n_batch is
// sorted, each wave accumulates a register float2 per lane for the current
// graph id and flushes with atomicAdd only when the id changes (or at range
// end). Atomic count ~ (#waves * segments-per-range * 128) << N*128.

#define BLOCK_THREADS 256
#define GRID_BLOCKS   1024   // 4096 waves -> ~122 nodes/wave, 16 waves/CU

__global__ __launch_bounds__(BLOCK_THREADS)
void n2g_attention_kernel(const float* __restrict__ n_emb,
                          const float* __restrict__ g_emb,
                          const int*   __restrict__ n_batch,
                          float* __restrict__ out,
                          int N)
{
    const int waves_per_block = BLOCK_THREADS >> 6;
    const int wave_id   = blockIdx.x * waves_per_block + (threadIdx.x >> 6);
    const int lane      = threadIdx.x & 63;
    const int num_waves = GRID_BLOCKS * waves_per_block;

    const int per   = (N + num_waves - 1) / num_waves;
    const int start = wave_id * per;
    const int end   = min(start + per, N);
    if (start >= N) return;

    const int col = 2 * lane;  // this lane's column pair

    float2 acc = make_float2(0.0f, 0.0f);
    int cur_g = n_batch[start];  // wave-uniform (same node for all lanes)

    for (int i = start; i < end; ++i) {
        const int g = n_batch[i];
        if (g != cur_g) {
            // segment boundary: flush accumulator for cur_g
            atomicAdd(&out[(size_t)cur_g * 128 + col],     acc.x);
            atomicAdd(&out[(size_t)cur_g * 128 + col + 1], acc.y);
            acc = make_float2(0.0f, 0.0f);
            cur_g = g;
        }
        const float2 nv = *(const float2*)(n_emb + (size_t)i * 128 + col);
        const float2 gv = *(const float2*)(g_emb + (size_t)g * 128 + col);

        float d = nv.x * gv.x + nv.y * gv.y;
        // wave-wide sum (64 lanes)
        #pragma unroll
        for (int off = 32; off > 0; off >>= 1)
            d += __shfl_xor(d, off, 64);

        const float c = 1.0f / (1.0f + __expf(-d));
        acc.x += c * nv.x;
        acc.y += c * nv.y;
    }
    // final flush
    atomicAdd(&out[(size_t)cur_g * 128 + col],     acc.x);
    atomicAdd(&out[(size_t)cur_g * 128 + col + 1], acc.y);
}

extern "C" void kernel_launch(void* const* d_in, const int* in_sizes, int n_in,
                              void* d_out, int out_size, void* d_ws, size_t ws_size,
                              hipStream_t stream) {
    const float* n_emb   = (const float*)d_in[0];
    const float* g_emb   = (const float*)d_in[1];
    const int*   n_batch = (const int*)d_in[2];
    // d_in[3] is `size` (G) on device; G is implied by out_size = G*128.
    float* out = (float*)d_out;
    const int N = in_sizes[2];  // one batch id per node

    // harness poisons d_out with 0xAA before every replay -> zero it first
    hipMemsetAsync(d_out, 0, (size_t)out_size * sizeof(float), stream);

    n2g_attention_kernel<<<GRID_BLOCKS, BLOCK_THREADS, 0, stream>>>(
        n_emb, g_emb, n_batch, out, N);
}

// Round 2
// 362.581 us; speedup vs baseline: 1.2729x; 1.2729x over previous
//
#include <hip/hip_runtime.h>
#include <math.h>

// Node2GraphAttention: out[g] = sum_{i: batch[i]==g} sigmoid(<n_i, g_emb[g]>) * n_i
// N=500000, D=128, G=10000, n_batch sorted ascending.
//
// R2 structure: one HALF-WAVE (32 lanes) per contiguous node range; lane owns
// a float4 (cols 4*(l&31) .. +3). Dot = in-lane dot4 + 5-step __shfl_xor
// (masks 1..16 stay inside the 32-lane half). Unroll U=4 nodes/iteration so
// 8 independent 16 B loads are in flight and 4 shuffle chains interleave —
// attacks the R1 latency-bound chain (~4000 cy/node measured).
// Sorted batch => register accumulator, atomicAdd flush only on id change.

#define BLOCK_THREADS 256
#define GRID_BLOCKS   2048
#define U 4

__global__ __launch_bounds__(BLOCK_THREADS)
void n2g_attention_kernel(const float* __restrict__ n_emb,
                          const float* __restrict__ g_emb,
                          const int*   __restrict__ n_batch,
                          float* __restrict__ out,
                          int N)
{
    const int hw_in_block = threadIdx.x >> 5;              // half-wave id in block: 0..7
    const int hw_id       = blockIdx.x * (BLOCK_THREADS >> 5) + hw_in_block;
    const int l32         = threadIdx.x & 31;
    const int col         = l32 * 4;
    const int num_hw      = GRID_BLOCKS * (BLOCK_THREADS >> 5);

    const int per   = (N + num_hw - 1) / num_hw;
    const int start = hw_id * per;
    const int end   = min(start + per, N);
    if (start >= N) return;

    float4 acc = make_float4(0.f, 0.f, 0.f, 0.f);
    int cur_g = n_batch[start];

    int i = start;

    // main unrolled loop: U nodes per iteration
    for (; i + U <= end; i += U) {
        int    gj[U];
        float4 nv[U], gv[U];

        #pragma unroll
        for (int j = 0; j < U; ++j) gj[j] = n_batch[i + j];
        #pragma unroll
        for (int j = 0; j < U; ++j)
            nv[j] = *(const float4*)(n_emb + (size_t)(i + j) * 128 + col);
        #pragma unroll
        for (int j = 0; j < U; ++j)
            gv[j] = *(const float4*)(g_emb + (size_t)gj[j] * 128 + col);

        float d[U];
        #pragma unroll
        for (int j = 0; j < U; ++j)
            d[j] = nv[j].x * gv[j].x + nv[j].y * gv[j].y
                 + nv[j].z * gv[j].z + nv[j].w * gv[j].w;

        // 5-step butterfly within each 32-lane half; 4 chains interleaved
        #pragma unroll
        for (int m = 1; m <= 16; m <<= 1) {
            #pragma unroll
            for (int j = 0; j < U; ++j)
                d[j] += __shfl_xor(d[j], m, 64);
        }

        #pragma unroll
        for (int j = 0; j < U; ++j) {
            const float c = 1.0f / (1.0f + __expf(-d[j]));
            if (gj[j] != cur_g) {
                atomicAdd(&out[(size_t)cur_g * 128 + col + 0], acc.x);
                atomicAdd(&out[(size_t)cur_g * 128 + col + 1], acc.y);
                atomicAdd(&out[(size_t)cur_g * 128 + col + 2], acc.z);
                atomicAdd(&out[(size_t)cur_g * 128 + col + 3], acc.w);
                acc = make_float4(0.f, 0.f, 0.f, 0.f);
                cur_g = gj[j];
            }
            acc.x += c * nv[j].x;
            acc.y += c * nv[j].y;
            acc.z += c * nv[j].z;
            acc.w += c * nv[j].w;
        }
    }

    // tail: one node at a time
    for (; i < end; ++i) {
        const int g = n_batch[i];
        const float4 nv = *(const float4*)(n_emb + (size_t)i * 128 + col);
        const float4 gv = *(const float4*)(g_emb + (size_t)g * 128 + col);
        float d = nv.x * gv.x + nv.y * gv.y + nv.z * gv.z + nv.w * gv.w;
        #pragma unroll
        for (int m = 1; m <= 16; m <<= 1)
            d += __shfl_xor(d, m, 64);
        const float c = 1.0f / (1.0f + __expf(-d));
        if (g != cur_g) {
            atomicAdd(&out[(size_t)cur_g * 128 + col + 0], acc.x);
            atomicAdd(&out[(size_t)cur_g * 128 + col + 1], acc.y);
            atomicAdd(&out[(size_t)cur_g * 128 + col + 2], acc.z);
            atomicAdd(&out[(size_t)cur_g * 128 + col + 3], acc.w);
            acc = make_float4(0.f, 0.f, 0.f, 0.f);
            cur_g = g;
        }
        acc.x += c * nv.x;
        acc.y += c * nv.y;
        acc.z += c * nv.z;
        acc.w += c * nv.w;
    }

    // final flush
    atomicAdd(&out[(size_t)cur_g * 128 + col + 0], acc.x);
    atomicAdd(&out[(size_t)cur_g * 128 + col + 1], acc.y);
    atomicAdd(&out[(size_t)cur_g * 128 + col + 2], acc.z);
    atomicAdd(&out[(size_t)cur_g * 128 + col + 3], acc.w);
}

extern "C" void kernel_launch(void* const* d_in, const int* in_sizes, int n_in,
                              void* d_out, int out_size, void* d_ws, size_t ws_size,
                              hipStream_t stream) {
    const float* n_emb   = (const float*)d_in[0];
    const float* g_emb   = (const float*)d_in[1];
    const int*   n_batch = (const int*)d_in[2];
    float* out = (float*)d_out;
    const int N = in_sizes[2];

    // harness poisons d_out with 0xAA before every replay -> zero it first
    hipMemsetAsync(d_out, 0, (size_t)out_size * sizeof(float), stream);

    n2g_attention_kernel<<<GRID_BLOCKS, BLOCK_THREADS, 0, stream>>>(
        n_emb, g_emb, n_batch, out, N);
}

// Round 3
// 355.326 us; speedup vs baseline: 1.2989x; 1.0204x over previous
//
#include <hip/hip_runtime.h>
#include <math.h>

// Node2GraphAttention: out[g] = sum_{i: batch[i]==g} sigmoid(<n_i, g_emb[g]>) * n_i
// N=500000, D=128, G=10000, n_batch sorted ascending.
//
// R3: half-wave (32 lanes) per contiguous node range, lane owns float4 cols.
// KEY: g-row cached in registers (gv); reloaded only on graph-id change.
// Fast path (whole U=8 group same graph, ~92% of groups given avg run=50):
// 2 int4 batch loads + 8 independent float4 n-row loads, NO dependent loads,
// addresses pure in i -> deep pipelining. Slow path handles boundaries with
// atomicAdd flush. Range length rounded to U: for N=500k, 16384 halves ->
// per=32 exactly, no tail anywhere.

#define BLOCK_THREADS 256
#define GRID_BLOCKS   2048
#define U 8

__device__ __forceinline__ float dot4(float4 a, float4 b) {
    return a.x * b.x + a.y * b.y + a.z * b.z + a.w * b.w;
}

__global__ __launch_bounds__(BLOCK_THREADS)
void n2g_attention_kernel(const float* __restrict__ n_emb,
                          const float* __restrict__ g_emb,
                          const int*   __restrict__ n_batch,
                          float* __restrict__ out,
                          int N)
{
    const int hw_id  = blockIdx.x * (BLOCK_THREADS >> 5) + (threadIdx.x >> 5);
    const int l32    = threadIdx.x & 31;
    const int col    = l32 * 4;
    const int num_hw = GRID_BLOCKS * (BLOCK_THREADS >> 5);

    int per = (N + num_hw - 1) / num_hw;
    per = (per + U - 1) & ~(U - 1);          // multiple of U (alignment + no tail)
    const int start = hw_id * per;
    if (start >= N) return;
    const int end = min(start + per, N);

    float4 acc = make_float4(0.f, 0.f, 0.f, 0.f);
    int    cur_g = n_batch[start];
    float4 gv = *(const float4*)(g_emb + (size_t)cur_g * 128 + col);

    int i = start;
    for (; i + U <= end; i += U) {
        const int4 b0 = *(const int4*)(n_batch + i);
        const int4 b1 = *(const int4*)(n_batch + i + 4);

        float4 nv[U];
        #pragma unroll
        for (int j = 0; j < U; ++j)
            nv[j] = *(const float4*)(n_emb + (size_t)(i + j) * 128 + col);

        if (b1.w == cur_g) {
            // ---- fast path: whole group belongs to cur_g ----
            float d[U];
            #pragma unroll
            for (int j = 0; j < U; ++j) d[j] = dot4(nv[j], gv);

            #pragma unroll
            for (int m = 1; m <= 16; m <<= 1) {
                #pragma unroll
                for (int j = 0; j < U; ++j) d[j] += __shfl_xor(d[j], m, 64);
            }

            #pragma unroll
            for (int j = 0; j < U; ++j) {
                const float c = 1.0f / (1.0f + __expf(-d[j]));
                acc.x += c * nv[j].x;
                acc.y += c * nv[j].y;
                acc.z += c * nv[j].z;
                acc.w += c * nv[j].w;
            }
        } else {
            // ---- slow path: group crosses >=1 graph boundary ----
            const int b[U] = {b0.x, b0.y, b0.z, b0.w, b1.x, b1.y, b1.z, b1.w};
            #pragma unroll
            for (int j = 0; j < U; ++j) {
                if (b[j] != cur_g) {
                    atomicAdd(&out[(size_t)cur_g * 128 + col + 0], acc.x);
                    atomicAdd(&out[(size_t)cur_g * 128 + col + 1], acc.y);
                    atomicAdd(&out[(size_t)cur_g * 128 + col + 2], acc.z);
                    atomicAdd(&out[(size_t)cur_g * 128 + col + 3], acc.w);
                    acc = make_float4(0.f, 0.f, 0.f, 0.f);
                    cur_g = b[j];
                    gv = *(const float4*)(g_emb + (size_t)cur_g * 128 + col);
                }
                float d = dot4(nv[j], gv);
                #pragma unroll
                for (int m = 1; m <= 16; m <<= 1) d += __shfl_xor(d, m, 64);
                const float c = 1.0f / (1.0f + __expf(-d));
                acc.x += c * nv[j].x;
                acc.y += c * nv[j].y;
                acc.z += c * nv[j].z;
                acc.w += c * nv[j].w;
            }
        }
    }

    // generic tail (unused for N=500000 with this grid, kept for safety)
    for (; i < end; ++i) {
        const int g = n_batch[i];
        if (g != cur_g) {
            atomicAdd(&out[(size_t)cur_g * 128 + col + 0], acc.x);
            atomicAdd(&out[(size_t)cur_g * 128 + col + 1], acc.y);
            atomicAdd(&out[(size_t)cur_g * 128 + col + 2], acc.z);
            atomicAdd(&out[(size_t)cur_g * 128 + col + 3], acc.w);
            acc = make_float4(0.f, 0.f, 0.f, 0.f);
            cur_g = g;
            gv = *(const float4*)(g_emb + (size_t)cur_g * 128 + col);
        }
        const float4 nv = *(const float4*)(n_emb + (size_t)i * 128 + col);
        float d = dot4(nv, gv);
        #pragma unroll
        for (int m = 1; m <= 16; m <<= 1) d += __shfl_xor(d, m, 64);
        const float c = 1.0f / (1.0f + __expf(-d));
        acc.x += c * nv.x;
        acc.y += c * nv.y;
        acc.z += c * nv.z;
        acc.w += c * nv.w;
    }

    atomicAdd(&out[(size_t)cur_g * 128 + col + 0], acc.x);
    atomicAdd(&out[(size_t)cur_g * 128 + col + 1], acc.y);
    atomicAdd(&out[(size_t)cur_g * 128 + col + 2], acc.z);
    atomicAdd(&out[(size_t)cur_g * 128 + col + 3], acc.w);
}

extern "C" void kernel_launch(void* const* d_in, const int* in_sizes, int n_in,
                              void* d_out, int out_size, void* d_ws, size_t ws_size,
                              hipStream_t stream) {
    const float* n_emb   = (const float*)d_in[0];
    const float* g_emb   = (const float*)d_in[1];
    const int*   n_batch = (const int*)d_in[2];
    float* out = (float*)d_out;
    const int N = in_sizes[2];

    hipMemsetAsync(d_out, 0, (size_t)out_size * sizeof(float), stream);

    n2g_attention_kernel<<<GRID_BLOCKS, BLOCK_THREADS, 0, stream>>>(
        n_emb, g_emb, n_batch, out, N);
}